// Round 1
// baseline (450.149 us; speedup 1.0000x reference)
//
#include <hip/hip_runtime.h>
#include <math.h>

// Problem constants (B,C,H,W = 4,64,64,64)
#define N     4096          // H*W
#define B     4
#define C     64
#define DQK   8
#define DV    32
#define SCHUNK 8            // split-K chunks over keys
#define KEYS_PER_CHUNK (N / SCHUNK)   // 512
#define QB    (N / 256)     // query blocks per batch = 16

// ---------------------------------------------------------------------------
// Kernel 1: spectral-norm scales. One block (1 wave, 64 thr) per weight.
// sigma = u1 . (w v1), v1 = l2n(w^T u), u1 = l2n(w v1)  =>  sigma = ||t||^2/(||t||+eps)
// scale = 1/sigma. Note: the reference's v_* inputs are unused by _sn.
// ---------------------------------------------------------------------------
__global__ __launch_bounds__(64) void sigma_kernel(
    const float* __restrict__ w_theta, const float* __restrict__ w_phi,
    const float* __restrict__ w_g,     const float* __restrict__ w_o,
    const float* __restrict__ u_theta, const float* __restrict__ u_phi,
    const float* __restrict__ u_g,     const float* __restrict__ u_o,
    float* __restrict__ scales) {
  int which = blockIdx.x;
  const float* w; const float* u; int M, K;
  if      (which == 0) { w = w_theta; u = u_theta; M = DQK; K = C;  }
  else if (which == 1) { w = w_phi;   u = u_phi;   M = DQK; K = C;  }
  else if (which == 2) { w = w_g;     u = u_g;     M = DV;  K = C;  }
  else                 { w = w_o;     u = u_o;     M = C;   K = DV; }

  int tid = threadIdx.x;
  __shared__ float v1[64];

  // v1_raw[k] = sum_m w[m,k]*u[m]
  float acc = 0.f;
  if (tid < K) {
    for (int m = 0; m < M; ++m) acc += w[m * K + tid] * u[m];
  }
  float ss = acc * acc;
  #pragma unroll
  for (int off = 32; off; off >>= 1) ss += __shfl_xor(ss, off);
  float nrm = sqrtf(ss);
  v1[tid] = (tid < K) ? acc / (nrm + 1e-12f) : 0.f;
  __syncthreads();

  // t[m] = sum_k w[m,k]*v1[k]
  float t = 0.f;
  if (tid < M) {
    for (int k = 0; k < K; ++k) t += w[tid * K + k] * v1[k];
  }
  float ts = t * t;
  #pragma unroll
  for (int off = 32; off; off >>= 1) ts += __shfl_xor(ts, off);
  float tn = sqrtf(ts);
  // sigma = ts/(tn+eps); store 1/sigma
  if (tid == 0) scales[which] = (tn + 1e-12f) / ts;
}

// ---------------------------------------------------------------------------
// Kernel 2: projections theta/phi/g for every (b, n) column.
// Writes: phi_buf[b][8][N] (queries, coalesced loads later)
//         kv_buf [b][N][40] = {theta col (8), g col (32)} per key, contiguous.
// Weight loads are wave-uniform -> compiler scalarizes (SGPR operands, no LDS).
// ---------------------------------------------------------------------------
__global__ __launch_bounds__(256) void proj_kernel(
    const float* __restrict__ x,
    const float* __restrict__ w_theta, const float* __restrict__ w_phi,
    const float* __restrict__ w_g,
    const float* __restrict__ scales,
    float* __restrict__ phi_buf, float* __restrict__ kv_buf) {
  int t = blockIdx.x * 256 + threadIdx.x;   // [0, B*N)
  int b = t >> 12;
  int n = t & (N - 1);

  const float* xp = x + (size_t)b * C * N + n;
  float xv[C];
  #pragma unroll
  for (int c = 0; c < C; ++c) xv[c] = xp[(size_t)c * N];

  float s0 = scales[0], s1 = scales[1], s2 = scales[2];

  float th[DQK], ph[DQK], gg[DV];
  #pragma unroll
  for (int r = 0; r < DQK; ++r) {
    const float* wr = w_theta + r * C;
    float a = 0.f;
    #pragma unroll
    for (int c = 0; c < C; ++c) a += wr[c] * xv[c];
    th[r] = a * s0;
  }
  #pragma unroll
  for (int r = 0; r < DQK; ++r) {
    const float* wr = w_phi + r * C;
    float a = 0.f;
    #pragma unroll
    for (int c = 0; c < C; ++c) a += wr[c] * xv[c];
    ph[r] = a * s1;
  }
  #pragma unroll
  for (int r = 0; r < DV; ++r) {
    const float* wr = w_g + r * C;
    float a = 0.f;
    #pragma unroll
    for (int c = 0; c < C; ++c) a += wr[c] * xv[c];
    gg[r] = a * s2;
  }

  // phi (queries), layout [b][c][n] for coalesced per-row loads
  #pragma unroll
  for (int r = 0; r < DQK; ++r)
    phi_buf[((size_t)b * DQK + r) * N + n] = ph[r];

  // kv: per key contiguous {k[8], v[32]}
  float4* kvp = (float4*)(kv_buf + ((size_t)b * N + n) * 40);
  kvp[0] = make_float4(th[0], th[1], th[2], th[3]);
  kvp[1] = make_float4(th[4], th[5], th[6], th[7]);
  #pragma unroll
  for (int q = 0; q < 8; ++q)
    kvp[2 + q] = make_float4(gg[4*q], gg[4*q+1], gg[4*q+2], gg[4*q+3]);
}

// ---------------------------------------------------------------------------
// Kernel 3: flash attention over a key chunk; one thread = one query.
// Lazy-rescale online softmax (o[32] rescaled only on max update).
// grid = B * QB * SCHUNK blocks of 256.
// ---------------------------------------------------------------------------
__global__ __launch_bounds__(256) void attn_kernel(
    const float* __restrict__ phi_buf, const float* __restrict__ kv_buf,
    float* __restrict__ pm, float* __restrict__ pl, float* __restrict__ po) {
  int bi = blockIdx.x;
  int s  = bi % SCHUNK;
  int qb = (bi / SCHUNK) % QB;
  int b  = bi / (SCHUNK * QB);
  int j  = qb * 256 + threadIdx.x;

  float q[DQK];
  #pragma unroll
  for (int c = 0; c < DQK; ++c) q[c] = phi_buf[((size_t)b * DQK + c) * N + j];

  float m = -INFINITY, l = 0.f;
  float o[DV];
  #pragma unroll
  for (int c = 0; c < DV; ++c) o[c] = 0.f;

  const float4* kvb = (const float4*)kv_buf;
  int k0 = s * KEYS_PER_CHUNK;

  for (int i = k0; i < k0 + KEYS_PER_CHUNK; ++i) {
    const float4* kp = kvb + ((size_t)b * N + i) * 10;  // uniform address
    float4 ka = kp[0];
    float4 kb = kp[1];
    float4 v0 = kp[2], v1 = kp[3], v2 = kp[4], v3 = kp[5];
    float4 v4 = kp[6], v5 = kp[7], v6 = kp[8], v7 = kp[9];

    float sc = q[0]*ka.x + q[1]*ka.y + q[2]*ka.z + q[3]*ka.w
             + q[4]*kb.x + q[5]*kb.y + q[6]*kb.z + q[7]*kb.w;

    float p;
    if (sc > m) {                // rare after warm-up
      float corr = __expf(m - sc);   // exp(-inf)=0 on first key: correct init
      l *= corr;
      #pragma unroll
      for (int c = 0; c < DV; ++c) o[c] *= corr;
      m = sc;
      p = 1.f;
    } else {
      p = __expf(sc - m);
    }
    l += p;

    o[0]  += p*v0.x; o[1]  += p*v0.y; o[2]  += p*v0.z; o[3]  += p*v0.w;
    o[4]  += p*v1.x; o[5]  += p*v1.y; o[6]  += p*v1.z; o[7]  += p*v1.w;
    o[8]  += p*v2.x; o[9]  += p*v2.y; o[10] += p*v2.z; o[11] += p*v2.w;
    o[12] += p*v3.x; o[13] += p*v3.y; o[14] += p*v3.z; o[15] += p*v3.w;
    o[16] += p*v4.x; o[17] += p*v4.y; o[18] += p*v4.z; o[19] += p*v4.w;
    o[20] += p*v5.x; o[21] += p*v5.y; o[22] += p*v5.z; o[23] += p*v5.w;
    o[24] += p*v6.x; o[25] += p*v6.y; o[26] += p*v6.z; o[27] += p*v6.w;
    o[28] += p*v7.x; o[29] += p*v7.y; o[30] += p*v7.z; o[31] += p*v7.w;
  }

  size_t base = ((size_t)b * SCHUNK + s) * N + j;
  pm[base] = m;
  pl[base] = l;
  #pragma unroll
  for (int c = 0; c < DV; ++c)
    po[(((size_t)b * SCHUNK + s) * DV + c) * N + j] = o[c];
}

// ---------------------------------------------------------------------------
// Kernel 4: merge split-K partials + w_o projection + gamma*out + x.
// One thread per (b, j). w_o (scaled by gamma/sigma_o) staged in LDS.
// ---------------------------------------------------------------------------
__global__ __launch_bounds__(256) void combine_kernel(
    const float* __restrict__ x,
    const float* __restrict__ w_o, const float* __restrict__ scales,
    const float* __restrict__ gamma,
    const float* __restrict__ pm, const float* __restrict__ pl,
    const float* __restrict__ po,
    float* __restrict__ out) {
  __shared__ float wsh[C * DV];   // 2048 floats
  int tid = threadIdx.x;
  float swo = scales[3] * gamma[0];
  for (int idx = tid; idx < C * DV; idx += 256) wsh[idx] = w_o[idx] * swo;
  __syncthreads();

  int t = blockIdx.x * 256 + tid;
  int b = t >> 12;
  int j = t & (N - 1);

  float mc[SCHUNK];
  float M = -INFINITY;
  #pragma unroll
  for (int s = 0; s < SCHUNK; ++s) {
    mc[s] = pm[((size_t)b * SCHUNK + s) * N + j];
    M = fmaxf(M, mc[s]);
  }

  float L = 0.f;
  float o[DV];
  #pragma unroll
  for (int c = 0; c < DV; ++c) o[c] = 0.f;

  #pragma unroll
  for (int s = 0; s < SCHUNK; ++s) {
    float corr = __expf(mc[s] - M);
    L += pl[((size_t)b * SCHUNK + s) * N + j] * corr;
    #pragma unroll
    for (int c = 0; c < DV; ++c)
      o[c] += po[(((size_t)b * SCHUNK + s) * DV + c) * N + j] * corr;
  }

  float rL = 1.f / L;   // L >= 1 (the chunk holding the max contributes p=1)
  #pragma unroll
  for (int c = 0; c < DV; ++c) o[c] *= rL;

  const float* xp = x   + (size_t)b * C * N + j;
  float*       op = out + (size_t)b * C * N + j;
  #pragma unroll
  for (int oc = 0; oc < C; ++oc) {
    float r = 0.f;
    #pragma unroll
    for (int c = 0; c < DV; ++c) r += wsh[oc * DV + c] * o[c];
    op[(size_t)oc * N] = r + xp[(size_t)oc * N];
  }
}

// ---------------------------------------------------------------------------
extern "C" void kernel_launch(void* const* d_in, const int* in_sizes, int n_in,
                              void* d_out, int out_size, void* d_ws, size_t ws_size,
                              hipStream_t stream) {
  const float* x       = (const float*)d_in[0];
  const float* w_theta = (const float*)d_in[1];
  const float* w_phi   = (const float*)d_in[2];
  const float* w_g     = (const float*)d_in[3];
  const float* w_o     = (const float*)d_in[4];
  const float* gamma   = (const float*)d_in[5];
  const float* u_theta = (const float*)d_in[6];
  const float* u_phi   = (const float*)d_in[8];
  const float* u_g     = (const float*)d_in[10];
  const float* u_o     = (const float*)d_in[12];

  float* ws      = (float*)d_ws;
  float* scales  = ws;                                  // 16 floats (4 used)
  float* phi_buf = ws + 16;                             // B*8*N   = 131072
  float* kv_buf  = phi_buf + (size_t)B * DQK * N;       // B*N*40  = 655360 (16B-aligned)
  float* pm      = kv_buf  + (size_t)B * N * 40;        // B*S*N   = 131072
  float* pl      = pm      + (size_t)B * SCHUNK * N;    // B*S*N   = 131072
  float* po      = pl      + (size_t)B * SCHUNK * N;    // B*S*32*N = 4194304
  // total ~21 MB of workspace

  float* out = (float*)d_out;

  sigma_kernel<<<4, 64, 0, stream>>>(w_theta, w_phi, w_g, w_o,
                                     u_theta, u_phi, u_g, u_o, scales);
  proj_kernel<<<(B * N) / 256, 256, 0, stream>>>(x, w_theta, w_phi, w_g,
                                                 scales, phi_buf, kv_buf);
  attn_kernel<<<B * QB * SCHUNK, 256, 0, stream>>>(phi_buf, kv_buf, pm, pl, po);
  combine_kernel<<<(B * N) / 256, 256, 0, stream>>>(x, w_o, scales, gamma,
                                                    pm, pl, po, out);
}

// Round 2
// 241.565 us; speedup vs baseline: 1.8635x; 1.8635x over previous
//
#include <hip/hip_runtime.h>
#include <math.h>

// Problem constants (B,C,H,W = 4,64,64,64)
#define N     4096          // H*W
#define B     4
#define C     64
#define DQK   8
#define DV    32
#define QB    (N / 256)     // query blocks per batch = 16

// ---------------------------------------------------------------------------
// Kernel 1: spectral-norm scales. One block (1 wave, 64 thr) per weight.
// sigma = ||t||^2/(||t||+eps), t = w * l2n(w^T u). scale = 1/sigma.
// ---------------------------------------------------------------------------
__global__ __launch_bounds__(64) void sigma_kernel(
    const float* __restrict__ w_theta, const float* __restrict__ w_phi,
    const float* __restrict__ w_g,     const float* __restrict__ w_o,
    const float* __restrict__ u_theta, const float* __restrict__ u_phi,
    const float* __restrict__ u_g,     const float* __restrict__ u_o,
    float* __restrict__ scales) {
  int which = blockIdx.x;
  const float* w; const float* u; int M, K;
  if      (which == 0) { w = w_theta; u = u_theta; M = DQK; K = C;  }
  else if (which == 1) { w = w_phi;   u = u_phi;   M = DQK; K = C;  }
  else if (which == 2) { w = w_g;     u = u_g;     M = DV;  K = C;  }
  else                 { w = w_o;     u = u_o;     M = C;   K = DV; }

  int tid = threadIdx.x;
  __shared__ float v1[64];

  float acc = 0.f;
  if (tid < K) {
    for (int m = 0; m < M; ++m) acc += w[m * K + tid] * u[m];
  }
  float ss = acc * acc;
  #pragma unroll
  for (int off = 32; off; off >>= 1) ss += __shfl_xor(ss, off);
  float nrm = sqrtf(ss);
  v1[tid] = (tid < K) ? acc / (nrm + 1e-12f) : 0.f;
  __syncthreads();

  float t = 0.f;
  if (tid < M) {
    for (int k = 0; k < K; ++k) t += w[tid * K + k] * v1[k];
  }
  float ts = t * t;
  #pragma unroll
  for (int off = 32; off; off >>= 1) ts += __shfl_xor(ts, off);
  float tn = sqrtf(ts);
  if (tid == 0) scales[which] = (tn + 1e-12f) / ts;
}

// ---------------------------------------------------------------------------
// Kernel 2: projections. One thread per (b, n, row-octet g in [0,6)).
// g=0: theta rows 0-7 -> kv[0:8]; g=1: phi rows -> phi_buf; g=2..5: g rows -> kv[8:40].
// 6x more waves than one-thread-per-column (1536 waves); x re-read 6x hits L2.
// ---------------------------------------------------------------------------
__global__ __launch_bounds__(256) void proj_kernel(
    const float* __restrict__ x,
    const float* __restrict__ w_theta, const float* __restrict__ w_phi,
    const float* __restrict__ w_g,
    const float* __restrict__ scales,
    float* __restrict__ phi_buf, float* __restrict__ kv_buf) {
  int t  = blockIdx.x * 256 + threadIdx.x;   // [0, B*6*N)
  int n  = t & (N - 1);
  int bg = t >> 12;
  int g  = bg % 6;          // wave-uniform (N spans 64 waves per g)
  int b  = bg / 6;

  const float* xp = x + (size_t)b * C * N + n;
  float xv[C];
  #pragma unroll
  for (int c = 0; c < C; ++c) xv[c] = xp[(size_t)c * N];

  const float* wbase; float s;
  if      (g == 0) { wbase = w_theta;           s = scales[0]; }
  else if (g == 1) { wbase = w_phi;             s = scales[1]; }
  else             { wbase = w_g + (g - 2) * 8 * C; s = scales[2]; }

  float o[8];
  #pragma unroll
  for (int r = 0; r < 8; ++r) {
    const float* wr = wbase + r * C;
    float a = 0.f;
    #pragma unroll
    for (int c = 0; c < C; ++c) a += wr[c] * xv[c];
    o[r] = a * s;
  }

  if (g == 1) {
    #pragma unroll
    for (int r = 0; r < 8; ++r)
      phi_buf[((size_t)b * DQK + r) * N + n] = o[r];
  } else {
    int off = (g == 0) ? 0 : 8 + (g - 2) * 8;
    float4* kp = (float4*)(kv_buf + ((size_t)b * N + n) * 40 + off);
    kp[0] = make_float4(o[0], o[1], o[2], o[3]);
    kp[1] = make_float4(o[4], o[5], o[6], o[7]);
  }
}

// ---------------------------------------------------------------------------
// Kernel 3: flash attention over a key chunk; one thread = one query.
// Lazy-rescale online softmax. grid = B * QB * S blocks of 256.
// ---------------------------------------------------------------------------
template <int S>
__global__ __launch_bounds__(256) void attn_kernel(
    const float* __restrict__ phi_buf, const float* __restrict__ kv_buf,
    float* __restrict__ pm, float* __restrict__ pl, float* __restrict__ po) {
  constexpr int KPC = N / S;
  int bi = blockIdx.x;
  int s  = bi % S;
  int qb = (bi / S) % QB;
  int b  = bi / (S * QB);
  int j  = qb * 256 + threadIdx.x;

  float q[DQK];
  #pragma unroll
  for (int c = 0; c < DQK; ++c) q[c] = phi_buf[((size_t)b * DQK + c) * N + j];

  float m = -INFINITY, l = 0.f;
  float o[DV];
  #pragma unroll
  for (int c = 0; c < DV; ++c) o[c] = 0.f;

  const float4* kvb = (const float4*)kv_buf;
  int k0 = s * KPC;

  #pragma unroll 2
  for (int i = k0; i < k0 + KPC; ++i) {
    const float4* kp = kvb + ((size_t)b * N + i) * 10;  // wave-uniform address
    float4 ka = kp[0];
    float4 kb = kp[1];
    float4 v0 = kp[2], v1 = kp[3], v2 = kp[4], v3 = kp[5];
    float4 v4 = kp[6], v5 = kp[7], v6 = kp[8], v7 = kp[9];

    float sc = q[0]*ka.x + q[1]*ka.y + q[2]*ka.z + q[3]*ka.w
             + q[4]*kb.x + q[5]*kb.y + q[6]*kb.z + q[7]*kb.w;

    float p;
    if (sc > m) {
      float corr = __expf(m - sc);   // exp(-inf)=0 on first key
      l *= corr;
      #pragma unroll
      for (int c = 0; c < DV; ++c) o[c] *= corr;
      m = sc;
      p = 1.f;
    } else {
      p = __expf(sc - m);
    }
    l += p;

    o[0]  += p*v0.x; o[1]  += p*v0.y; o[2]  += p*v0.z; o[3]  += p*v0.w;
    o[4]  += p*v1.x; o[5]  += p*v1.y; o[6]  += p*v1.z; o[7]  += p*v1.w;
    o[8]  += p*v2.x; o[9]  += p*v2.y; o[10] += p*v2.z; o[11] += p*v2.w;
    o[12] += p*v3.x; o[13] += p*v3.y; o[14] += p*v3.z; o[15] += p*v3.w;
    o[16] += p*v4.x; o[17] += p*v4.y; o[18] += p*v4.z; o[19] += p*v4.w;
    o[20] += p*v5.x; o[21] += p*v5.y; o[22] += p*v5.z; o[23] += p*v5.w;
    o[24] += p*v6.x; o[25] += p*v6.y; o[26] += p*v6.z; o[27] += p*v6.w;
    o[28] += p*v7.x; o[29] += p*v7.y; o[30] += p*v7.z; o[31] += p*v7.w;
  }

  size_t base = ((size_t)b * S + s) * N + j;
  pm[base] = m;
  pl[base] = l;
  #pragma unroll
  for (int c = 0; c < DV; ++c)
    po[(((size_t)b * S + s) * DV + c) * N + j] = o[c];
}

// ---------------------------------------------------------------------------
// Kernel 4a: merge split-K partials. One thread per (b, v-channel c, j).
// Writes normalized o to obuf[b][c][j].
// ---------------------------------------------------------------------------
template <int S>
__global__ __launch_bounds__(256) void combineA_kernel(
    const float* __restrict__ pm, const float* __restrict__ pl,
    const float* __restrict__ po, float* __restrict__ obuf) {
  int t = blockIdx.x * 256 + threadIdx.x;   // [0, B*DV*N)
  int j = t & (N - 1);
  int c = (t >> 12) & (DV - 1);
  int b = t >> 17;

  float mc[S];
  float M = -INFINITY;
  #pragma unroll
  for (int s = 0; s < S; ++s) {
    mc[s] = pm[((size_t)b * S + s) * N + j];
    M = fmaxf(M, mc[s]);
  }

  float L = 0.f, o = 0.f;
  #pragma unroll
  for (int s = 0; s < S; ++s) {
    float corr = __expf(mc[s] - M);
    L += pl[((size_t)b * S + s) * N + j] * corr;
    o += po[(((size_t)b * S + s) * DV + c) * N + j] * corr;
  }
  obuf[((size_t)b * DV + c) * N + j] = o / L;   // L >= 1
}

// ---------------------------------------------------------------------------
// Kernel 4b: out[b][oc][j] = gamma/sigma_o * sum_c w_o[oc][c]*obuf[b][c][j] + x.
// One thread per output element; w row wave-uniform (scalar loads).
// ---------------------------------------------------------------------------
__global__ __launch_bounds__(256) void combineB_kernel(
    const float* __restrict__ x,
    const float* __restrict__ w_o, const float* __restrict__ scales,
    const float* __restrict__ gamma,
    const float* __restrict__ obuf, float* __restrict__ out) {
  int t  = blockIdx.x * 256 + threadIdx.x;   // [0, B*C*N)
  int j  = t & (N - 1);
  int oc = (t >> 12) & (C - 1);
  int b  = t >> 18;

  float swo = scales[3] * gamma[0];
  const float* wr = w_o + oc * DV;           // wave-uniform
  const float* op = obuf + (size_t)b * DV * N + j;

  float r = 0.f;
  #pragma unroll
  for (int c = 0; c < DV; ++c) r += wr[c] * op[(size_t)c * N];

  out[t] = swo * r + x[t];
}

// ---------------------------------------------------------------------------
extern "C" void kernel_launch(void* const* d_in, const int* in_sizes, int n_in,
                              void* d_out, int out_size, void* d_ws, size_t ws_size,
                              hipStream_t stream) {
  const float* x       = (const float*)d_in[0];
  const float* w_theta = (const float*)d_in[1];
  const float* w_phi   = (const float*)d_in[2];
  const float* w_g     = (const float*)d_in[3];
  const float* w_o     = (const float*)d_in[4];
  const float* gamma   = (const float*)d_in[5];
  const float* u_theta = (const float*)d_in[6];
  const float* u_phi   = (const float*)d_in[8];
  const float* u_g     = (const float*)d_in[10];
  const float* u_o     = (const float*)d_in[12];
  float* out = (float*)d_out;

  float* ws = (float*)d_ws;

  // Shared (S-independent) sections
  float* scales  = ws;                                  // 16
  float* phi_buf = ws + 16;                             // B*8*N   = 131072
  float* kv_buf  = phi_buf + (size_t)B * DQK * N;       // B*N*40  = 655360
  float* obuf    = kv_buf  + (size_t)B * N * 40;        // B*DV*N  = 524288
  float* pm      = obuf    + (size_t)B * DV * N;        // B*S*N
  // pl, po follow; sizes depend on S.

  sigma_kernel<<<4, 64, 0, stream>>>(w_theta, w_phi, w_g, w_o,
                                     u_theta, u_phi, u_g, u_o, scales);
  proj_kernel<<<(B * 6 * N) / 256, 256, 0, stream>>>(x, w_theta, w_phi, w_g,
                                                     scales, phi_buf, kv_buf);

  size_t fixed = 16 + (size_t)B * DQK * N + (size_t)B * N * 40 + (size_t)B * DV * N;
  size_t need32 = (fixed + (size_t)B * 32 * N * (2 + DV)) * sizeof(float);

  if (ws_size >= need32) {
    constexpr int S = 32;
    float* pl = pm + (size_t)B * S * N;
    float* po = pl + (size_t)B * S * N;
    attn_kernel<S><<<B * QB * S, 256, 0, stream>>>(phi_buf, kv_buf, pm, pl, po);
    combineA_kernel<S><<<(B * DV * N) / 256, 256, 0, stream>>>(pm, pl, po, obuf);
  } else {
    constexpr int S = 8;
    float* pl = pm + (size_t)B * S * N;
    float* po = pl + (size_t)B * S * N;
    attn_kernel<S><<<B * QB * S, 256, 0, stream>>>(phi_buf, kv_buf, pm, pl, po);
    combineA_kernel<S><<<(B * DV * N) / 256, 256, 0, stream>>>(pm, pl, po, obuf);
  }

  combineB_kernel<<<(B * C * N) / 256, 256, 0, stream>>>(x, w_o, scales, gamma,
                                                         obuf, out);
}

// Round 3
// 183.775 us; speedup vs baseline: 2.4495x; 1.3145x over previous
//
#include <hip/hip_runtime.h>
#include <math.h>

// Problem constants (B,C,H,W = 4,64,64,64)
#define N     4096          // H*W
#define B     4
#define C     64
#define DQK   8
#define DV    32
#define S     16            // key chunks (one per wave over 4 blocks of 4 waves)
#define LOG2E 1.4426950408889634f

typedef __attribute__((ext_vector_type(8)))  short  short8;   // 8 bf16 (4 VGPR)
typedef __attribute__((ext_vector_type(16))) float  float16;  // MFMA 32x32 acc

union U4S8 { int4 v; unsigned int u[4]; short8 s; };

__device__ __forceinline__ unsigned short f2bf(float f) {   // RNE
  union { float f; unsigned int u; } c; c.f = f;
  unsigned int r = c.u + 0x7FFF + ((c.u >> 16) & 1);
  return (unsigned short)(r >> 16);
}
__device__ __forceinline__ unsigned int fbits(float f) {
  union { float f; unsigned int u; } c; c.f = f; return c.u;
}

// ---------------------------------------------------------------------------
// Kernel 1: spectral-norm scales. One block (1 wave) per weight.
// sigma = ||t||^2/(||t||+eps), t = w * l2n(w^T u). scale = 1/sigma.
// ---------------------------------------------------------------------------
__global__ __launch_bounds__(64) void sigma_kernel(
    const float* __restrict__ w_theta, const float* __restrict__ w_phi,
    const float* __restrict__ w_g,     const float* __restrict__ w_o,
    const float* __restrict__ u_theta, const float* __restrict__ u_phi,
    const float* __restrict__ u_g,     const float* __restrict__ u_o,
    float* __restrict__ scales) {
  int which = blockIdx.x;
  const float* w; const float* u; int M, K;
  if      (which == 0) { w = w_theta; u = u_theta; M = DQK; K = C;  }
  else if (which == 1) { w = w_phi;   u = u_phi;   M = DQK; K = C;  }
  else if (which == 2) { w = w_g;     u = u_g;     M = DV;  K = C;  }
  else                 { w = w_o;     u = u_o;     M = C;   K = DV; }

  int tid = threadIdx.x;
  __shared__ float v1[64];

  float acc = 0.f;
  if (tid < K) {
    for (int m = 0; m < M; ++m) acc += w[m * K + tid] * u[m];
  }
  float ss = acc * acc;
  #pragma unroll
  for (int off = 32; off; off >>= 1) ss += __shfl_xor(ss, off);
  float nrm = sqrtf(ss);
  v1[tid] = (tid < K) ? acc / (nrm + 1e-12f) : 0.f;
  __syncthreads();

  float t = 0.f;
  if (tid < M) {
    for (int k = 0; k < K; ++k) t += w[tid * K + k] * v1[k];
  }
  float ts = t * t;
  #pragma unroll
  for (int off = 32; off; off >>= 1) ts += __shfl_xor(ts, off);
  float tn = sqrtf(ts);
  if (tid == 0) scales[which] = (tn + 1e-12f) / ts;
}

// ---------------------------------------------------------------------------
// Kernel 2: projections -> bf16 buffers for MFMA.
//   theta_bf[b][n][8]  (per-key contiguous, 16B)   = scaled theta
//   phi_bf  [b][n][8]  (per-query contiguous, 16B) = scaled phi
//   v_bf    [b][c][n]  (transposed)                = scaled g
// One thread per (b, n, octet g in [0,6)).
// ---------------------------------------------------------------------------
__global__ __launch_bounds__(256) void proj_kernel(
    const float* __restrict__ x,
    const float* __restrict__ w_theta, const float* __restrict__ w_phi,
    const float* __restrict__ w_g,
    const float* __restrict__ scales,
    unsigned short* __restrict__ theta_bf,
    unsigned short* __restrict__ phi_bf,
    unsigned short* __restrict__ v_bf) {
  int t  = blockIdx.x * 256 + threadIdx.x;   // [0, B*6*N)
  int n  = t & (N - 1);
  int bg = t >> 12;
  int g  = bg % 6;          // wave-uniform
  int b  = bg / 6;

  const float* xp = x + (size_t)b * C * N + n;
  float xv[C];
  #pragma unroll
  for (int c = 0; c < C; ++c) xv[c] = xp[(size_t)c * N];

  const float* wbase; float s;
  if      (g == 0) { wbase = w_theta;               s = scales[0]; }
  else if (g == 1) { wbase = w_phi;                 s = scales[1]; }
  else             { wbase = w_g + (g - 2) * 8 * C; s = scales[2]; }

  float o[8];
  #pragma unroll
  for (int r = 0; r < 8; ++r) {
    const float* wr = wbase + r * C;
    float a = 0.f;
    #pragma unroll
    for (int c = 0; c < C; ++c) a += wr[c] * xv[c];
    o[r] = a * s;
  }

  if (g < 2) {
    U4S8 u;
    #pragma unroll
    for (int r = 0; r < 8; ++r) u.s[r] = (short)f2bf(o[r]);
    unsigned short* dst = (g == 0) ? theta_bf : phi_bf;
    *(int4*)(dst + ((size_t)b * N + n) * 8) = u.v;
  } else {
    int c0 = (g - 2) * 8;
    #pragma unroll
    for (int r = 0; r < 8; ++r)
      v_bf[((size_t)b * DV + c0 + r) * N + n] = f2bf(o[r]);
  }
}

// ---------------------------------------------------------------------------
// Kernel 3: MFMA flash attention.
// Block = 4 waves, 32 queries; wave w handles key chunk sc = (bi&3)*4+w (256 keys).
// Per 32-key tile: 1 score MFMA (32x32x16, K padded 8->16 via zeroed phi half),
// online softmax in C-layout regs, p->bf16, shfl_xor(32) C->B relayout,
// 2 PV MFMAs. Partials (m,l,o[32]) per (b,sc,query) to workspace.
// ---------------------------------------------------------------------------
__global__ __launch_bounds__(256) void attn_kernel(
    const unsigned short* __restrict__ theta_bf,
    const unsigned short* __restrict__ phi_bf,
    const unsigned short* __restrict__ v_bf,
    float* __restrict__ pm, float* __restrict__ pl, float* __restrict__ po) {
  int bi = blockIdx.x;                 // B * 128 * 4
  int s4 = bi & 3;
  int qt = (bi >> 2) & 127;
  int b  = bi >> 9;
  int lane = threadIdx.x & 63;
  int wav  = threadIdx.x >> 6;
  int sc   = s4 * 4 + wav;             // 0..15
  int half = lane >> 5;
  int l31  = lane & 31;
  int j    = qt * 32 + l31;            // query column

  // phi B-frag: lane(n=j, k=half*8+i); zero high K-half (dqk=8 pad to 16)
  U4S8 phu; phu.u[0] = phu.u[1] = phu.u[2] = phu.u[3] = 0;
  if (half == 0)
    phu.v = *(const int4*)(phi_bf + ((size_t)b * N + j) * 8);
  short8 phB = phu.s;

  float m = -INFINITY, l = 0.f;
  float16 o;
  #pragma unroll
  for (int r = 0; r < 16; ++r) o[r] = 0.f;

  const unsigned short* vrow = v_bf + ((size_t)b * DV + l31) * N;
  int kstart = sc * (N / S);           // 256 keys per wave

  #pragma unroll 2
  for (int tt = 0; tt < (N / S) / 32; ++tt) {
    int kb = kstart + tt * 32;

    // theta A-frag: lane(m=key l31, k=half*8+i); high-K garbage * zero phi = 0
    U4S8 ta; ta.v = *(const int4*)(theta_bf + ((size_t)b * N + kb + l31) * 8);
    // V A-frags for PV (M=channel l31, K=keys)
    U4S8 va1; va1.v = *(const int4*)(vrow + kb + half * 8);
    U4S8 va2; va2.v = *(const int4*)(vrow + kb + 16 + half * 8);

    float16 sf;
    #pragma unroll
    for (int r = 0; r < 16; ++r) sf[r] = 0.f;
    sf = __builtin_amdgcn_mfma_f32_32x32x16_bf16(ta.s, phB, sf, 0, 0, 0);
    // sf[r]: score for key kb + (r&3)+8*(r>>2)+4*half, query j

    // --- online softmax over this 32-key tile ---
    float tm = sf[0];
    #pragma unroll
    for (int r = 1; r < 16; ++r) tm = fmaxf(tm, sf[r]);
    tm = fmaxf(tm, __shfl_xor(tm, 32));
    float mn = fmaxf(m, tm);
    float alpha = __expf(m - mn);       // m=-inf first tile -> 0
    m = mn;
    float base = mn * LOG2E;
    float p[16];
    float tl = 0.f;
    #pragma unroll
    for (int r = 0; r < 16; ++r) {
      p[r] = exp2f(fmaf(sf[r], LOG2E, -base));
      tl += p[r];
    }
    tl += __shfl_xor(tl, 32);
    l = fmaf(l, alpha, tl);
    #pragma unroll
    for (int r = 0; r < 16; ++r) o[r] *= alpha;

    // pack p -> bf16 pairs (truncation; error ~2^-8 rel, fine for budget)
    unsigned int pk[8];
    #pragma unroll
    for (int i = 0; i < 8; ++i)
      pk[i] = __builtin_amdgcn_perm(fbits(p[2 * i + 1]), fbits(p[2 * i]),
                                    0x07060302u);
    // C-layout -> B-operand layout: exchange across lane pairs (xor 32).
    // half0 holds keys {0-3,8-11,16-19,24-27}, half1 {4-7,12-15,20-23,28-31}.
    unsigned int s1a = half ? pk[0] : pk[2];
    unsigned int s1b = half ? pk[1] : pk[3];
    unsigned int r1a = __shfl_xor(s1a, 32);
    unsigned int r1b = __shfl_xor(s1b, 32);
    unsigned int s2a = half ? pk[4] : pk[6];
    unsigned int s2b = half ? pk[5] : pk[7];
    unsigned int r2a = __shfl_xor(s2a, 32);
    unsigned int r2b = __shfl_xor(s2b, 32);

    U4S8 b1, b2;
    b1.u[0] = half ? r1a  : pk[0];   // keys 0-1   | 8-9
    b1.u[1] = half ? r1b  : pk[1];   // keys 2-3   | 10-11
    b1.u[2] = half ? pk[2] : r1a;    // keys 4-5   | 12-13
    b1.u[3] = half ? pk[3] : r1b;    // keys 6-7   | 14-15
    b2.u[0] = half ? r2a  : pk[4];   // keys 16-17 | 24-25
    b2.u[1] = half ? r2b  : pk[5];   // keys 18-19 | 26-27
    b2.u[2] = half ? pk[6] : r2a;    // keys 20-21 | 28-29
    b2.u[3] = half ? pk[7] : r2b;    // keys 22-23 | 30-31

    o = __builtin_amdgcn_mfma_f32_32x32x16_bf16(va1.s, b1.s, o, 0, 0, 0);
    o = __builtin_amdgcn_mfma_f32_32x32x16_bf16(va2.s, b2.s, o, 0, 0, 0);
  }

  // store partials: o[r] is channel c=(r&3)+8*(r>>2)+4*half, query j
  size_t pbase = ((size_t)b * S + sc) * DV;
  #pragma unroll
  for (int r = 0; r < 16; ++r) {
    int c = (r & 3) + 8 * (r >> 2) + 4 * half;
    po[(pbase + c) * N + j] = o[r];
  }
  if (half == 0) {
    pm[((size_t)b * S + sc) * N + j] = m;
    pl[((size_t)b * S + sc) * N + j] = l;
  }
}

// ---------------------------------------------------------------------------
// Kernel 4: fused combine: merge S chunks -> normalized o (LDS) -> w_o proj
// -> gamma*out + x. Block = 64 queries x 4 waves; wave w merges channel
// octet w in phase 1, computes output channels w*16..w*16+15 in phase 2.
// ---------------------------------------------------------------------------
__global__ __launch_bounds__(256) void combine_kernel(
    const float* __restrict__ x,
    const float* __restrict__ w_o, const float* __restrict__ scales,
    const float* __restrict__ gamma,
    const float* __restrict__ pm, const float* __restrict__ pl,
    const float* __restrict__ po,
    float* __restrict__ out) {
  __shared__ float wsh[C * DV];     // 8 KB
  __shared__ float ot[DV][64];      // 8 KB
  int b = blockIdx.x >> 6;
  int jbase = (blockIdx.x & 63) * 64;
  int t = threadIdx.x;
  float swo = scales[3] * gamma[0];
  for (int i = t; i < C * DV; i += 256) wsh[i] = w_o[i] * swo;

  int jj = t & 63;
  int q  = t >> 6;                  // wave index
  int j  = jbase + jj;

  float mc[S];
  float M = -INFINITY;
  #pragma unroll
  for (int s = 0; s < S; ++s) {
    mc[s] = pm[((size_t)b * S + s) * N + j];
    M = fmaxf(M, mc[s]);
  }
  float L = 0.f;
  float o8[8];
  #pragma unroll
  for (int r = 0; r < 8; ++r) o8[r] = 0.f;
  #pragma unroll
  for (int s = 0; s < S; ++s) {
    float al = __expf(mc[s] - M);
    L += pl[((size_t)b * S + s) * N + j] * al;
    const float* pp = po + (((size_t)b * S + s) * DV + q * 8) * N + j;
    #pragma unroll
    for (int r = 0; r < 8; ++r) o8[r] = fmaf(pp[(size_t)r * N], al, o8[r]);
  }
  float rL = 1.f / L;
  #pragma unroll
  for (int r = 0; r < 8; ++r) ot[q * 8 + r][jj] = o8[r] * rL;
  __syncthreads();

  const float* xb = x   + (size_t)b * C * N + jbase + jj;
  float*       ob = out + (size_t)b * C * N + jbase + jj;
  #pragma unroll
  for (int oi = 0; oi < 16; ++oi) {
    int oc = q * 16 + oi;
    float acc = 0.f;
    #pragma unroll
    for (int c = 0; c < DV; ++c) acc += wsh[oc * DV + c] * ot[c][jj];
    ob[(size_t)oc * N] = acc + xb[(size_t)oc * N];
  }
}

// ---------------------------------------------------------------------------
extern "C" void kernel_launch(void* const* d_in, const int* in_sizes, int n_in,
                              void* d_out, int out_size, void* d_ws, size_t ws_size,
                              hipStream_t stream) {
  const float* x       = (const float*)d_in[0];
  const float* w_theta = (const float*)d_in[1];
  const float* w_phi   = (const float*)d_in[2];
  const float* w_g     = (const float*)d_in[3];
  const float* w_o     = (const float*)d_in[4];
  const float* gamma   = (const float*)d_in[5];
  const float* u_theta = (const float*)d_in[6];
  const float* u_phi   = (const float*)d_in[8];
  const float* u_g     = (const float*)d_in[10];
  const float* u_o     = (const float*)d_in[12];
  float* out = (float*)d_out;

  float* ws = (float*)d_ws;
  float*          scales   = ws;                                   // 16 floats
  unsigned short* theta_bf = (unsigned short*)(ws + 16);           // B*N*8 bf16
  unsigned short* phi_bf   = theta_bf + (size_t)B * N * 8;         // B*N*8
  unsigned short* v_bf     = phi_bf   + (size_t)B * N * 8;         // B*DV*N
  float*          pm       = (float*)(v_bf + (size_t)B * DV * N);  // B*S*N
  float*          pl       = pm + (size_t)B * S * N;               // B*S*N
  float*          po       = pl + (size_t)B * S * N;               // B*S*DV*N (~33 MB)

  sigma_kernel<<<4, 64, 0, stream>>>(w_theta, w_phi, w_g, w_o,
                                     u_theta, u_phi, u_g, u_o, scales);
  proj_kernel<<<(B * 6 * N) / 256, 256, 0, stream>>>(
      x, w_theta, w_phi, w_g, scales, theta_bf, phi_bf, v_bf);
  attn_kernel<<<B * 128 * 4, 256, 0, stream>>>(
      theta_bf, phi_bf, v_bf, pm, pl, po);
  combine_kernel<<<B * (N / 64), 256, 0, stream>>>(
      x, w_o, scales, gamma, pm, pl, po, out);
}

// Round 4
// 154.405 us; speedup vs baseline: 2.9154x; 1.1902x over previous
//
#include <hip/hip_runtime.h>
#include <math.h>

// Problem constants (B,C,H,W = 4,64,64,64)
#define N     4096          // H*W
#define B     4
#define C     64
#define DQK   8
#define DV    32
#define S     16            // key chunks
#define LOG2E 1.4426950408889634f

typedef __attribute__((ext_vector_type(8)))  short  short8;   // 8 bf16 (4 VGPR)
typedef __attribute__((ext_vector_type(16))) float  float16;  // MFMA 32x32 acc

union U4S8 { int4 v; unsigned int u[4]; short8 s; };

__device__ __forceinline__ unsigned short f2bf(float f) {   // RNE
  union { float f; unsigned int u; } c; c.f = f;
  unsigned int r = c.u + 0x7FFF + ((c.u >> 16) & 1);
  return (unsigned short)(r >> 16);
}
__device__ __forceinline__ unsigned int fbits(float f) {
  union { float f; unsigned int u; } c; c.f = f; return c.u;
}

// ---------------------------------------------------------------------------
// Kernel 1: spectral-norm scales. One block (1 wave) per weight.
// ---------------------------------------------------------------------------
__global__ __launch_bounds__(64) void sigma_kernel(
    const float* __restrict__ w_theta, const float* __restrict__ w_phi,
    const float* __restrict__ w_g,     const float* __restrict__ w_o,
    const float* __restrict__ u_theta, const float* __restrict__ u_phi,
    const float* __restrict__ u_g,     const float* __restrict__ u_o,
    float* __restrict__ scales) {
  int which = blockIdx.x;
  const float* w; const float* u; int M, K;
  if      (which == 0) { w = w_theta; u = u_theta; M = DQK; K = C;  }
  else if (which == 1) { w = w_phi;   u = u_phi;   M = DQK; K = C;  }
  else if (which == 2) { w = w_g;     u = u_g;     M = DV;  K = C;  }
  else                 { w = w_o;     u = u_o;     M = C;   K = DV; }

  int tid = threadIdx.x;
  __shared__ float v1[64];

  float acc = 0.f;
  if (tid < K) {
    for (int m = 0; m < M; ++m) acc += w[m * K + tid] * u[m];
  }
  float ss = acc * acc;
  #pragma unroll
  for (int off = 32; off; off >>= 1) ss += __shfl_xor(ss, off);
  float nrm = sqrtf(ss);
  v1[tid] = (tid < K) ? acc / (nrm + 1e-12f) : 0.f;
  __syncthreads();

  float t = 0.f;
  if (tid < M) {
    for (int k = 0; k < K; ++k) t += w[tid * K + k] * v1[k];
  }
  float ts = t * t;
  #pragma unroll
  for (int off = 32; off; off >>= 1) ts += __shfl_xor(ts, off);
  float tn = sqrtf(ts);
  if (tid == 0) scales[which] = (tn + 1e-12f) / ts;
}

// ---------------------------------------------------------------------------
// Kernel 2: projections -> bf16 buffers. One thread per (b, n, quad g in [0,12)):
// g 0-1: theta rows g*4..g*4+3 -> theta_bf[b][n][8] (int2 store)
// g 2-3: phi  rows            -> phi_bf  [b][n][8] (int2 store)
// g 4-11: g   rows            -> v_bf[b][c][n] (transposed, scalar stores)
// 768 blocks / 3072 waves.
// ---------------------------------------------------------------------------
__global__ __launch_bounds__(256) void proj_kernel(
    const float* __restrict__ x,
    const float* __restrict__ w_theta, const float* __restrict__ w_phi,
    const float* __restrict__ w_g,
    const float* __restrict__ scales,
    unsigned short* __restrict__ theta_bf,
    unsigned short* __restrict__ phi_bf,
    unsigned short* __restrict__ v_bf) {
  int t  = blockIdx.x * 256 + threadIdx.x;   // [0, B*12*N)
  int n  = t & (N - 1);
  int bg = t >> 12;
  int g  = bg % 12;          // block-uniform
  int b  = bg / 12;

  const float* xp = x + (size_t)b * C * N + n;
  float xv[C];
  #pragma unroll
  for (int c = 0; c < C; ++c) xv[c] = xp[(size_t)c * N];

  const float* wbase; float s;
  if      (g < 2) { wbase = w_theta + g * 4 * C;       s = scales[0]; }
  else if (g < 4) { wbase = w_phi + (g - 2) * 4 * C;   s = scales[1]; }
  else            { wbase = w_g + (g - 4) * 4 * C;     s = scales[2]; }

  float o[4];
  #pragma unroll
  for (int r = 0; r < 4; ++r) {
    const float* wr = wbase + r * C;
    float a = 0.f;
    #pragma unroll
    for (int c = 0; c < C; ++c) a += wr[c] * xv[c];
    o[r] = a * s;
  }

  if (g < 4) {
    unsigned int lo = ((unsigned int)f2bf(o[0])) | ((unsigned int)f2bf(o[1]) << 16);
    unsigned int hi = ((unsigned int)f2bf(o[2])) | ((unsigned int)f2bf(o[3]) << 16);
    unsigned short* dst = (g < 2) ? theta_bf : phi_bf;
    int sub = g & 1;
    int2 pk; pk.x = (int)lo; pk.y = (int)hi;
    *(int2*)(dst + ((size_t)b * N + n) * 8 + sub * 4) = pk;
  } else {
    int c0 = (g - 4) * 4;
    #pragma unroll
    for (int r = 0; r < 4; ++r)
      v_bf[((size_t)b * DV + c0 + r) * N + n] = f2bf(o[r]);
  }
}

// ---------------------------------------------------------------------------
// Kernel 3: MFMA flash attention (unchanged from R3 — verified correct).
// Block = 4 waves, 32 queries; wave handles key chunk sc (256 keys).
// ---------------------------------------------------------------------------
__global__ __launch_bounds__(256) void attn_kernel(
    const unsigned short* __restrict__ theta_bf,
    const unsigned short* __restrict__ phi_bf,
    const unsigned short* __restrict__ v_bf,
    float* __restrict__ pm, float* __restrict__ pl, float* __restrict__ po) {
  int bi = blockIdx.x;                 // B * 128 * 4
  int s4 = bi & 3;
  int qt = (bi >> 2) & 127;
  int b  = bi >> 9;
  int lane = threadIdx.x & 63;
  int wav  = threadIdx.x >> 6;
  int sc   = s4 * 4 + wav;             // 0..15
  int half = lane >> 5;
  int l31  = lane & 31;
  int j    = qt * 32 + l31;            // query column

  U4S8 phu; phu.u[0] = phu.u[1] = phu.u[2] = phu.u[3] = 0;
  if (half == 0)
    phu.v = *(const int4*)(phi_bf + ((size_t)b * N + j) * 8);
  short8 phB = phu.s;

  float m = -INFINITY, l = 0.f;
  float16 o;
  #pragma unroll
  for (int r = 0; r < 16; ++r) o[r] = 0.f;

  const unsigned short* vrow = v_bf + ((size_t)b * DV + l31) * N;
  int kstart = sc * (N / S);           // 256 keys per wave

  #pragma unroll 2
  for (int tt = 0; tt < (N / S) / 32; ++tt) {
    int kb = kstart + tt * 32;

    U4S8 ta; ta.v = *(const int4*)(theta_bf + ((size_t)b * N + kb + l31) * 8);
    U4S8 va1; va1.v = *(const int4*)(vrow + kb + half * 8);
    U4S8 va2; va2.v = *(const int4*)(vrow + kb + 16 + half * 8);

    float16 sf;
    #pragma unroll
    for (int r = 0; r < 16; ++r) sf[r] = 0.f;
    sf = __builtin_amdgcn_mfma_f32_32x32x16_bf16(ta.s, phB, sf, 0, 0, 0);

    float tm = sf[0];
    #pragma unroll
    for (int r = 1; r < 16; ++r) tm = fmaxf(tm, sf[r]);
    tm = fmaxf(tm, __shfl_xor(tm, 32));
    float mn = fmaxf(m, tm);
    float alpha = __expf(m - mn);       // m=-inf first tile -> 0
    m = mn;
    float base = mn * LOG2E;
    float p[16];
    float tl = 0.f;
    #pragma unroll
    for (int r = 0; r < 16; ++r) {
      p[r] = exp2f(fmaf(sf[r], LOG2E, -base));
      tl += p[r];
    }
    tl += __shfl_xor(tl, 32);
    l = fmaf(l, alpha, tl);
    #pragma unroll
    for (int r = 0; r < 16; ++r) o[r] *= alpha;

    unsigned int pk[8];
    #pragma unroll
    for (int i = 0; i < 8; ++i)
      pk[i] = __builtin_amdgcn_perm(fbits(p[2 * i + 1]), fbits(p[2 * i]),
                                    0x07060302u);
    unsigned int s1a = half ? pk[0] : pk[2];
    unsigned int s1b = half ? pk[1] : pk[3];
    unsigned int r1a = __shfl_xor(s1a, 32);
    unsigned int r1b = __shfl_xor(s1b, 32);
    unsigned int s2a = half ? pk[4] : pk[6];
    unsigned int s2b = half ? pk[5] : pk[7];
    unsigned int r2a = __shfl_xor(s2a, 32);
    unsigned int r2b = __shfl_xor(s2b, 32);

    U4S8 b1, b2;
    b1.u[0] = half ? r1a  : pk[0];
    b1.u[1] = half ? r1b  : pk[1];
    b1.u[2] = half ? pk[2] : r1a;
    b1.u[3] = half ? pk[3] : r1b;
    b2.u[0] = half ? r2a  : pk[4];
    b2.u[1] = half ? r2b  : pk[5];
    b2.u[2] = half ? pk[6] : r2a;
    b2.u[3] = half ? pk[7] : r2b;

    o = __builtin_amdgcn_mfma_f32_32x32x16_bf16(va1.s, b1.s, o, 0, 0, 0);
    o = __builtin_amdgcn_mfma_f32_32x32x16_bf16(va2.s, b2.s, o, 0, 0, 0);
  }

  size_t pbase = ((size_t)b * S + sc) * DV;
  #pragma unroll
  for (int r = 0; r < 16; ++r) {
    int c = (r & 3) + 8 * (r >> 2) + 4 * half;
    po[(pbase + c) * N + j] = o[r];
  }
  if (half == 0) {
    pm[((size_t)b * S + sc) * N + j] = m;
    pl[((size_t)b * S + sc) * N + j] = l;
  }
}

// ---------------------------------------------------------------------------
// Kernel 4a: merge split-K partials. One thread per (b, c, j): 2048 blocks.
// ---------------------------------------------------------------------------
__global__ __launch_bounds__(256) void combineA_kernel(
    const float* __restrict__ pm, const float* __restrict__ pl,
    const float* __restrict__ po, float* __restrict__ obuf) {
  int t = blockIdx.x * 256 + threadIdx.x;   // [0, B*DV*N)
  int j = t & (N - 1);
  int c = (t >> 12) & (DV - 1);
  int b = t >> 17;

  float mc[S];
  float M = -INFINITY;
  #pragma unroll
  for (int s = 0; s < S; ++s) {
    mc[s] = pm[((size_t)b * S + s) * N + j];
    M = fmaxf(M, mc[s]);
  }

  float L = 0.f, o = 0.f;
  #pragma unroll
  for (int s = 0; s < S; ++s) {
    float corr = __expf(mc[s] - M);
    L += pl[((size_t)b * S + s) * N + j] * corr;
    o += po[(((size_t)b * S + s) * DV + c) * N + j] * corr;
  }
  obuf[((size_t)b * DV + c) * N + j] = o / L;   // L >= 1
}

// ---------------------------------------------------------------------------
// Kernel 4b: out[b][oc][j] = gamma/sigma_o * (w_o[oc] . obuf[b][:][j]) + x.
// One thread per output element; w row wave-uniform (scalar loads). 4096 blocks.
// ---------------------------------------------------------------------------
__global__ __launch_bounds__(256) void combineB_kernel(
    const float* __restrict__ x,
    const float* __restrict__ w_o, const float* __restrict__ scales,
    const float* __restrict__ gamma,
    const float* __restrict__ obuf, float* __restrict__ out) {
  int t  = blockIdx.x * 256 + threadIdx.x;   // [0, B*C*N)
  int j  = t & (N - 1);
  int oc = (t >> 12) & (C - 1);
  int b  = t >> 18;

  float swo = scales[3] * gamma[0];
  const float* wr = w_o + oc * DV;           // wave-uniform
  const float* op = obuf + (size_t)b * DV * N + j;

  float r = 0.f;
  #pragma unroll
  for (int c = 0; c < DV; ++c) r += wr[c] * op[(size_t)c * N];

  out[t] = swo * r + x[t];
}

// ---------------------------------------------------------------------------
extern "C" void kernel_launch(void* const* d_in, const int* in_sizes, int n_in,
                              void* d_out, int out_size, void* d_ws, size_t ws_size,
                              hipStream_t stream) {
  const float* x       = (const float*)d_in[0];
  const float* w_theta = (const float*)d_in[1];
  const float* w_phi   = (const float*)d_in[2];
  const float* w_g     = (const float*)d_in[3];
  const float* w_o     = (const float*)d_in[4];
  const float* gamma   = (const float*)d_in[5];
  const float* u_theta = (const float*)d_in[6];
  const float* u_phi   = (const float*)d_in[8];
  const float* u_g     = (const float*)d_in[10];
  const float* u_o     = (const float*)d_in[12];
  float* out = (float*)d_out;

  float* ws = (float*)d_ws;
  float*          scales   = ws;                                   // 16 floats
  unsigned short* theta_bf = (unsigned short*)(ws + 16);           // B*N*8 bf16
  unsigned short* phi_bf   = theta_bf + (size_t)B * N * 8;         // B*N*8
  unsigned short* v_bf     = phi_bf   + (size_t)B * N * 8;         // B*DV*N
  float*          pm       = (float*)(v_bf + (size_t)B * DV * N);  // B*S*N
  float*          pl       = pm + (size_t)B * S * N;               // B*S*N
  float*          po       = pl + (size_t)B * S * N;               // B*S*DV*N
  float*          obuf     = po + (size_t)B * S * DV * N;          // B*DV*N

  sigma_kernel<<<4, 64, 0, stream>>>(w_theta, w_phi, w_g, w_o,
                                     u_theta, u_phi, u_g, u_o, scales);
  proj_kernel<<<(B * 12 * N) / 256, 256, 0, stream>>>(
      x, w_theta, w_phi, w_g, scales, theta_bf, phi_bf, v_bf);
  attn_kernel<<<B * 128 * 4, 256, 0, stream>>>(
      theta_bf, phi_bf, v_bf, pm, pl, po);
  combineA_kernel<<<(B * DV * N) / 256, 256, 0, stream>>>(pm, pl, po, obuf);
  combineB_kernel<<<(B * C * N) / 256, 256, 0, stream>>>(x, w_o, scales, gamma,
                                                         obuf, out);
}

// Round 5
// 144.208 us; speedup vs baseline: 3.1215x; 1.0707x over previous
//
#include <hip/hip_runtime.h>
#include <math.h>

// Problem constants (B,C,H,W = 4,64,64,64)
#define N     4096          // H*W
#define B     4
#define C     64
#define DQK   8
#define DV    32
#define S     16            // key chunks
#define LOG2E 1.4426950408889634f

typedef __attribute__((ext_vector_type(8)))  short  short8;   // 8 bf16 (4 VGPR)
typedef __attribute__((ext_vector_type(16))) float  float16;  // MFMA 32x32 acc

union U4S8 { int4 v; unsigned int u[4]; short8 s; };

__device__ __forceinline__ unsigned short f2bf(float f) {   // RNE
  union { float f; unsigned int u; } c; c.f = f;
  unsigned int r = c.u + 0x7FFF + ((c.u >> 16) & 1);
  return (unsigned short)(r >> 16);
}
__device__ __forceinline__ float bf2f(unsigned short h) {
  union { unsigned int u; float f; } c; c.u = ((unsigned int)h) << 16;
  return c.f;
}
__device__ __forceinline__ unsigned int fbits(float f) {
  union { float f; unsigned int u; } c; c.f = f; return c.u;
}

// ---------------------------------------------------------------------------
// Kernel 1: spectral-norm scales. One block (1 wave) per weight.
// sigma = ||t||^2/(||t||+eps), t = w * l2n(w^T u). scale = 1/sigma.
// ---------------------------------------------------------------------------
__global__ __launch_bounds__(64) void sigma_kernel(
    const float* __restrict__ w_theta, const float* __restrict__ w_phi,
    const float* __restrict__ w_g,     const float* __restrict__ w_o,
    const float* __restrict__ u_theta, const float* __restrict__ u_phi,
    const float* __restrict__ u_g,     const float* __restrict__ u_o,
    float* __restrict__ scales) {
  int which = blockIdx.x;
  const float* w; const float* u; int M, K;
  if      (which == 0) { w = w_theta; u = u_theta; M = DQK; K = C;  }
  else if (which == 1) { w = w_phi;   u = u_phi;   M = DQK; K = C;  }
  else if (which == 2) { w = w_g;     u = u_g;     M = DV;  K = C;  }
  else                 { w = w_o;     u = u_o;     M = C;   K = DV; }

  int tid = threadIdx.x;
  __shared__ float v1[64];

  float acc = 0.f;
  if (tid < K) {
    for (int m = 0; m < M; ++m) acc += w[m * K + tid] * u[m];
  }
  float ss = acc * acc;
  #pragma unroll
  for (int off = 32; off; off >>= 1) ss += __shfl_xor(ss, off);
  float nrm = sqrtf(ss);
  v1[tid] = (tid < K) ? acc / (nrm + 1e-12f) : 0.f;
  __syncthreads();

  float t = 0.f;
  if (tid < M) {
    for (int k = 0; k < K; ++k) t += w[tid * K + k] * v1[k];
  }
  float ts = t * t;
  #pragma unroll
  for (int off = 32; off; off >>= 1) ts += __shfl_xor(ts, off);
  float tn = sqrtf(ts);
  if (tid == 0) scales[which] = (tn + 1e-12f) / ts;
}

// ---------------------------------------------------------------------------
// Kernel 2: projections -> bf16 buffers. One thread per (b, n, quad g in [0,12)):
// g 0-1: theta rows (scaled by 1/sigma * LOG2E) -> theta_bf[b][n][8]
// g 2-3: phi  rows -> phi_bf[b][n][8]
// g 4-11: g   rows -> v_bf[b][c][bitswap23(n)]  (key-permuted for MFMA relayout-free PV)
// ---------------------------------------------------------------------------
__global__ __launch_bounds__(256) void proj_kernel(
    const float* __restrict__ x,
    const float* __restrict__ w_theta, const float* __restrict__ w_phi,
    const float* __restrict__ w_g,
    const float* __restrict__ scales,
    unsigned short* __restrict__ theta_bf,
    unsigned short* __restrict__ phi_bf,
    unsigned short* __restrict__ v_bf) {
  int t  = blockIdx.x * 256 + threadIdx.x;   // [0, B*12*N)
  int n  = t & (N - 1);
  int bg = t >> 12;
  int g  = bg % 12;          // block-uniform
  int b  = bg / 12;

  const float* xp = x + (size_t)b * C * N + n;
  float xv[C];
  #pragma unroll
  for (int c = 0; c < C; ++c) xv[c] = xp[(size_t)c * N];

  const float* wbase; float s;
  if      (g < 2) { wbase = w_theta + g * 4 * C;       s = scales[0] * LOG2E; }
  else if (g < 4) { wbase = w_phi + (g - 2) * 4 * C;   s = scales[1]; }
  else            { wbase = w_g + (g - 4) * 4 * C;     s = scales[2]; }

  float o[4];
  #pragma unroll
  for (int r = 0; r < 4; ++r) {
    const float* wr = wbase + r * C;
    float a = 0.f;
    #pragma unroll
    for (int c = 0; c < C; ++c) a += wr[c] * xv[c];
    o[r] = a * s;
  }

  if (g < 4) {
    unsigned int lo = ((unsigned int)f2bf(o[0])) | ((unsigned int)f2bf(o[1]) << 16);
    unsigned int hi = ((unsigned int)f2bf(o[2])) | ((unsigned int)f2bf(o[3]) << 16);
    unsigned short* dst = (g < 2) ? theta_bf : phi_bf;
    int sub = g & 1;
    int2 pk; pk.x = (int)lo; pk.y = (int)hi;
    *(int2*)(dst + ((size_t)b * N + n) * 8 + sub * 4) = pk;
  } else {
    int c0 = (g - 4) * 4;
    // key permutation: swap bits 2<->3 (involution) so score C-layout regs
    // feed the PV B-operand directly (no cross-lane relayout in attn).
    int np = (n & ~0xC) | ((n & 4) << 1) | ((n & 8) >> 1);
    #pragma unroll
    for (int r = 0; r < 4; ++r)
      v_bf[((size_t)b * DV + c0 + r) * N + np] = f2bf(o[r]);
  }
}

// ---------------------------------------------------------------------------
// Kernel 3: MFMA flash attention, no online max (scores bounded: spectral-norm
// keeps |score| ~ O(10); exp2 domain safe in fp32/bf16). Scores arrive already
// in log2 domain (LOG2E folded into theta scale).
// Block = 4 waves, 32 queries; wave handles key chunk sc (256 keys).
// Per 32-key tile: 1 score MFMA, 16 exp2, 16 adds, 8 packs, 2 PV MFMAs.
// ---------------------------------------------------------------------------
__global__ __launch_bounds__(256) void attn_kernel(
    const unsigned short* __restrict__ theta_bf,
    const unsigned short* __restrict__ phi_bf,
    const unsigned short* __restrict__ v_bf,
    float* __restrict__ pl, unsigned short* __restrict__ po) {
  int bi = blockIdx.x;                 // B * 128 * 4
  int s4 = bi & 3;
  int qt = (bi >> 2) & 127;
  int b  = bi >> 9;
  int lane = threadIdx.x & 63;
  int wav  = threadIdx.x >> 6;
  int sc   = s4 * 4 + wav;             // 0..15
  int half = lane >> 5;
  int l31  = lane & 31;
  int j    = qt * 32 + l31;            // query column

  // phi B-frag: lane(n=j, k=half*8+i); zero high K-half (dqk=8 pad to 16)
  U4S8 phu; phu.u[0] = phu.u[1] = phu.u[2] = phu.u[3] = 0;
  if (half == 0)
    phu.v = *(const int4*)(phi_bf + ((size_t)b * N + j) * 8);
  short8 phB = phu.s;

  float lsum = 0.f;
  float16 o;
  #pragma unroll
  for (int r = 0; r < 16; ++r) o[r] = 0.f;

  const unsigned short* vrow = v_bf + ((size_t)b * DV + l31) * N;
  int kstart = sc * (N / S);           // 256 keys per wave

  #pragma unroll 2
  for (int tt = 0; tt < (N / S) / 32; ++tt) {
    int kb = kstart + tt * 32;

    U4S8 ta;  ta.v  = *(const int4*)(theta_bf + ((size_t)b * N + kb + l31) * 8);
    U4S8 va1; va1.v = *(const int4*)(vrow + kb + half * 8);
    U4S8 va2; va2.v = *(const int4*)(vrow + kb + 16 + half * 8);

    float16 sf;
    #pragma unroll
    for (int r = 0; r < 16; ++r) sf[r] = 0.f;
    sf = __builtin_amdgcn_mfma_f32_32x32x16_bf16(ta.s, phB, sf, 0, 0, 0);

    float p[16];
    #pragma unroll
    for (int r = 0; r < 16; ++r) {
      p[r] = exp2f(sf[r]);
      lsum += p[r];
    }

    unsigned int pk[8];
    #pragma unroll
    for (int i = 0; i < 8; ++i)
      pk[i] = __builtin_amdgcn_perm(fbits(p[2 * i + 1]), fbits(p[2 * i]),
                                    0x07060302u);
    // V storage is key-permuted (bitswap 2<->3), so C-layout regs ARE the
    // B-operand fragments: no cross-lane exchange.
    U4S8 b1, b2;
    b1.u[0] = pk[0]; b1.u[1] = pk[1]; b1.u[2] = pk[2]; b1.u[3] = pk[3];
    b2.u[0] = pk[4]; b2.u[1] = pk[5]; b2.u[2] = pk[6]; b2.u[3] = pk[7];

    o = __builtin_amdgcn_mfma_f32_32x32x16_bf16(va1.s, b1.s, o, 0, 0, 0);
    o = __builtin_amdgcn_mfma_f32_32x32x16_bf16(va2.s, b2.s, o, 0, 0, 0);
  }

  // each lane summed p over 16 key-slots; lane^32 has the complementary 16
  lsum += __shfl_xor(lsum, 32);

  size_t pbase = ((size_t)b * S + sc) * DV;
  #pragma unroll
  for (int r = 0; r < 16; ++r) {
    int c = (r & 3) + 8 * (r >> 2) + 4 * half;
    po[(pbase + c) * N + j] = f2bf(o[r]);
  }
  if (half == 0)
    pl[((size_t)b * S + sc) * N + j] = lsum;
}

// ---------------------------------------------------------------------------
// Kernel 4a: merge split-K partials (pure sums now). One thread per (b, c, j).
// ---------------------------------------------------------------------------
__global__ __launch_bounds__(256) void combineA_kernel(
    const float* __restrict__ pl, const unsigned short* __restrict__ po,
    float* __restrict__ obuf) {
  int t = blockIdx.x * 256 + threadIdx.x;   // [0, B*DV*N)
  int j = t & (N - 1);
  int c = (t >> 12) & (DV - 1);
  int b = t >> 17;

  float L = 0.f;
  #pragma unroll
  for (int s = 0; s < S; ++s)
    L += pl[((size_t)b * S + s) * N + j];

  float o = 0.f;
  #pragma unroll
  for (int s = 0; s < S; ++s)
    o += bf2f(po[(((size_t)b * S + s) * DV + c) * N + j]);

  obuf[((size_t)b * DV + c) * N + j] = o / L;
}

// ---------------------------------------------------------------------------
// Kernel 4b: out[b][oc][j] = gamma/sigma_o * (w_o[oc] . obuf[b][:][j]) + x.
// One thread per output element; w row wave-uniform (scalar loads).
// ---------------------------------------------------------------------------
__global__ __launch_bounds__(256) void combineB_kernel(
    const float* __restrict__ x,
    const float* __restrict__ w_o, const float* __restrict__ scales,
    const float* __restrict__ gamma,
    const float* __restrict__ obuf, float* __restrict__ out) {
  int t  = blockIdx.x * 256 + threadIdx.x;   // [0, B*C*N)
  int j  = t & (N - 1);
  int oc = (t >> 12) & (C - 1);
  int b  = t >> 18;

  float swo = scales[3] * gamma[0];
  const float* wr = w_o + oc * DV;           // wave-uniform
  const float* op = obuf + (size_t)b * DV * N + j;

  float r = 0.f;
  #pragma unroll
  for (int c = 0; c < DV; ++c) r += wr[c] * op[(size_t)c * N];

  out[t] = swo * r + x[t];
}

// ---------------------------------------------------------------------------
extern "C" void kernel_launch(void* const* d_in, const int* in_sizes, int n_in,
                              void* d_out, int out_size, void* d_ws, size_t ws_size,
                              hipStream_t stream) {
  const float* x       = (const float*)d_in[0];
  const float* w_theta = (const float*)d_in[1];
  const float* w_phi   = (const float*)d_in[2];
  const float* w_g     = (const float*)d_in[3];
  const float* w_o     = (const float*)d_in[4];
  const float* gamma   = (const float*)d_in[5];
  const float* u_theta = (const float*)d_in[6];
  const float* u_phi   = (const float*)d_in[8];
  const float* u_g     = (const float*)d_in[10];
  const float* u_o     = (const float*)d_in[12];
  float* out = (float*)d_out;

  float* ws = (float*)d_ws;
  float*          scales   = ws;                                   // 16 floats
  unsigned short* theta_bf = (unsigned short*)(ws + 16);           // B*N*8 bf16
  unsigned short* phi_bf   = theta_bf + (size_t)B * N * 8;         // B*N*8
  unsigned short* v_bf     = phi_bf   + (size_t)B * N * 8;         // B*DV*N
  unsigned short* po       = v_bf + (size_t)B * DV * N;            // B*S*DV*N bf16
  float*          pl       = (float*)(po + (size_t)B * S * DV * N);// B*S*N
  float*          obuf     = pl + (size_t)B * S * N;               // B*DV*N

  sigma_kernel<<<4, 64, 0, stream>>>(w_theta, w_phi, w_g, w_o,
                                     u_theta, u_phi, u_g, u_o, scales);
  proj_kernel<<<(B * 12 * N) / 256, 256, 0, stream>>>(
      x, w_theta, w_phi, w_g, scales, theta_bf, phi_bf, v_bf);
  attn_kernel<<<B * 128 * 4, 256, 0, stream>>>(
      theta_bf, phi_bf, v_bf, pl, po);
  combineA_kernel<<<(B * DV * N) / 256, 256, 0, stream>>>(pl, po, obuf);
  combineB_kernel<<<(B * C * N) / 256, 256, 0, stream>>>(x, w_o, scales, gamma,
                                                         obuf, out);
}

// Round 6
// 130.995 us; speedup vs baseline: 3.4364x; 1.1009x over previous
//
#include <hip/hip_runtime.h>
#include <math.h>

// Problem constants (B,C,H,W = 4,64,64,64)
#define N     4096          // H*W
#define B     4
#define C     64
#define DQK   8
#define DV    32
#define LOG2E 1.4426950408889634f
#define PROJ_BLOCKS ((B * 12 * N) / 256)   // 768

typedef __attribute__((ext_vector_type(8)))  short  short8;   // 8 bf16 (4 VGPR)
typedef __attribute__((ext_vector_type(16))) float  float16;  // MFMA 32x32 acc

union U4S8 { int4 v; unsigned int u[4]; short8 s; };

__device__ __forceinline__ unsigned short f2bf(float f) {   // RNE
  union { float f; unsigned int u; } c; c.f = f;
  unsigned int r = c.u + 0x7FFF + ((c.u >> 16) & 1);
  return (unsigned short)(r >> 16);
}
__device__ __forceinline__ float bf2f(unsigned short h) {
  union { unsigned int u; float f; } c; c.u = ((unsigned int)h) << 16;
  return c.f;
}
__device__ __forceinline__ unsigned int fbits(float f) {
  union { float f; unsigned int u; } c; c.f = f; return c.u;
}

// ---------------------------------------------------------------------------
// Kernel 1 (fat): blocks [0,768) = projections -> UNSCALED bf16 buffers;
// blocks [768,772) = spectral-norm sigma (concurrent — proj no longer needs
// scales; they are consumed only by the attention kernel).
//   proj thread = (b, n, quad g in [0,12)):
//     g 0-1: theta rows -> theta_bf[b][n][8]
//     g 2-3: phi  rows -> phi_bf  [b][n][8]
//     g 4-11: g  rows -> v_bf[b][c][bitswap23(n)]  (key-permuted: C-layout
//             score regs feed the PV B-operand with no cross-lane exchange)
// ---------------------------------------------------------------------------
__global__ __launch_bounds__(256) void projsig_kernel(
    const float* __restrict__ x,
    const float* __restrict__ w_theta, const float* __restrict__ w_phi,
    const float* __restrict__ w_g,     const float* __restrict__ w_o,
    const float* __restrict__ u_theta, const float* __restrict__ u_phi,
    const float* __restrict__ u_g,     const float* __restrict__ u_o,
    float* __restrict__ scales,
    unsigned short* __restrict__ theta_bf,
    unsigned short* __restrict__ phi_bf,
    unsigned short* __restrict__ v_bf) {
  __shared__ float v1[64];
  int bid = blockIdx.x;
  int tid = threadIdx.x;

  if (bid >= PROJ_BLOCKS) {
    // ---- sigma: 1/sigma, sigma = ||t||^2/(||t||+eps), t = w * l2n(w^T u) ----
    int which = bid - PROJ_BLOCKS;
    const float* w; const float* u; int M, K;
    if      (which == 0) { w = w_theta; u = u_theta; M = DQK; K = C;  }
    else if (which == 1) { w = w_phi;   u = u_phi;   M = DQK; K = C;  }
    else if (which == 2) { w = w_g;     u = u_g;     M = DV;  K = C;  }
    else                 { w = w_o;     u = u_o;     M = C;   K = DV; }

    float acc = 0.f;
    if (tid < K) {
      for (int m = 0; m < M; ++m) acc += w[m * K + tid] * u[m];
    }
    float ss = acc * acc;
    #pragma unroll
    for (int off = 32; off; off >>= 1) ss += __shfl_xor(ss, off);
    float nrm = sqrtf(ss);
    if (tid < 64) v1[tid] = (tid < K) ? acc / (nrm + 1e-12f) : 0.f;
    __syncthreads();

    float t = 0.f;
    if (tid < M) {
      for (int k = 0; k < K; ++k) t += w[tid * K + k] * v1[k];
    }
    float ts = t * t;
    #pragma unroll
    for (int off = 32; off; off >>= 1) ts += __shfl_xor(ts, off);
    float tn = sqrtf(ts);
    if (tid == 0) scales[which] = (tn + 1e-12f) / ts;
    return;
  }

  // ---- projections ----
  int t  = bid * 256 + tid;   // [0, B*12*N)
  int n  = t & (N - 1);
  int bg = t >> 12;
  int g  = bg % 12;           // block-uniform
  int b  = bg / 12;

  const float* xp = x + (size_t)b * C * N + n;
  float xv[C];
  #pragma unroll
  for (int c = 0; c < C; ++c) xv[c] = xp[(size_t)c * N];

  const float* wbase;
  if      (g < 2) wbase = w_theta + g * 4 * C;
  else if (g < 4) wbase = w_phi + (g - 2) * 4 * C;
  else            wbase = w_g + (g - 4) * 4 * C;

  float o[4];
  #pragma unroll
  for (int r = 0; r < 4; ++r) {
    const float* wr = wbase + r * C;
    float a = 0.f;
    #pragma unroll
    for (int c = 0; c < C; ++c) a += wr[c] * xv[c];
    o[r] = a;
  }

  if (g < 4) {
    unsigned int lo = ((unsigned int)f2bf(o[0])) | ((unsigned int)f2bf(o[1]) << 16);
    unsigned int hi = ((unsigned int)f2bf(o[2])) | ((unsigned int)f2bf(o[3]) << 16);
    unsigned short* dst = (g < 2) ? theta_bf : phi_bf;
    int sub = g & 1;
    int2 pk; pk.x = (int)lo; pk.y = (int)hi;
    *(int2*)(dst + ((size_t)b * N + n) * 8 + sub * 4) = pk;
  } else {
    int c0 = (g - 4) * 4;
    // key permutation: swap bits 2<->3 (involution)
    int np = (n & ~0xC) | ((n & 4) << 1) | ((n & 8) >> 1);
    #pragma unroll
    for (int r = 0; r < 4; ++r)
      v_bf[((size_t)b * DV + c0 + r) * N + np] = f2bf(o[r]);
  }
}

// ---------------------------------------------------------------------------
// Kernel 2: fully fused MFMA attention + combine + w_o projection + residual.
// Block = 1024 threads (16 waves) = one query tile (32 queries) x ALL keys.
// Wave w handles keys [w*256, w*256+256). No online max (scores bounded by
// spectral norm; exp2 domain safe). kappa = s0*s1*log2e applied post-MFMA.
// Epilogue: LDS merge of 16 waves' (o[32ch], l) partials, normalize, then
// out[64,32] = (s2*s3*gamma) * w_o[64,32] @ o[32,32] + x, written directly.
// ---------------------------------------------------------------------------
__global__ __launch_bounds__(1024) void attn_kernel(
    const unsigned short* __restrict__ theta_bf,
    const unsigned short* __restrict__ phi_bf,
    const unsigned short* __restrict__ v_bf,
    const float* __restrict__ w_o, const float* __restrict__ scales,
    const float* __restrict__ gamma,
    const float* __restrict__ x, float* __restrict__ out) {
  __shared__ unsigned short po_lds[16][16][64];  // [wave][reg][lane] 32 KB
  __shared__ float l_lds[16][32];                // 2 KB
  __shared__ float Lrcp[32];
  __shared__ float ot[DV][33];                   // normalized o tile, padded
  __shared__ float wsh[C * DV];                  // scaled w_o, 8 KB

  int bi = blockIdx.x;           // B * 128
  int qt = bi & 127;
  int b  = bi >> 7;
  int tid  = threadIdx.x;
  int lane = tid & 63;
  int wav  = tid >> 6;           // 0..15
  int half = lane >> 5;
  int l31  = lane & 31;
  int j    = qt * 32 + l31;      // query column

  float kappa = scales[0] * scales[1] * LOG2E;
  float swo   = scales[2] * scales[3] * gamma[0];
  for (int i = tid; i < C * DV; i += 1024) wsh[i] = w_o[i] * swo;

  // phi B-frag: lane(n=j, k=half*8+i); zero high K-half (dqk=8 pad to 16)
  U4S8 phu; phu.u[0] = phu.u[1] = phu.u[2] = phu.u[3] = 0;
  if (half == 0)
    phu.v = *(const int4*)(phi_bf + ((size_t)b * N + j) * 8);
  short8 phB = phu.s;

  float lsum = 0.f;
  float16 o;
  #pragma unroll
  for (int r = 0; r < 16; ++r) o[r] = 0.f;

  const unsigned short* vrow = v_bf + ((size_t)b * DV + l31) * N;
  int kstart = wav * 256;

  #pragma unroll 2
  for (int tt = 0; tt < 8; ++tt) {
    int kb = kstart + tt * 32;

    U4S8 ta;  ta.v  = *(const int4*)(theta_bf + ((size_t)b * N + kb + l31) * 8);
    U4S8 va1; va1.v = *(const int4*)(vrow + kb + half * 8);
    U4S8 va2; va2.v = *(const int4*)(vrow + kb + 16 + half * 8);

    float16 sf;
    #pragma unroll
    for (int r = 0; r < 16; ++r) sf[r] = 0.f;
    sf = __builtin_amdgcn_mfma_f32_32x32x16_bf16(ta.s, phB, sf, 0, 0, 0);

    float p[16];
    #pragma unroll
    for (int r = 0; r < 16; ++r) {
      p[r] = exp2f(kappa * sf[r]);
      lsum += p[r];
    }

    unsigned int pk[8];
    #pragma unroll
    for (int i = 0; i < 8; ++i)
      pk[i] = __builtin_amdgcn_perm(fbits(p[2 * i + 1]), fbits(p[2 * i]),
                                    0x07060302u);
    // V storage is key-permuted: C-layout regs ARE the B-operand fragments.
    U4S8 b1, b2;
    b1.u[0] = pk[0]; b1.u[1] = pk[1]; b1.u[2] = pk[2]; b1.u[3] = pk[3];
    b2.u[0] = pk[4]; b2.u[1] = pk[5]; b2.u[2] = pk[6]; b2.u[3] = pk[7];

    o = __builtin_amdgcn_mfma_f32_32x32x16_bf16(va1.s, b1.s, o, 0, 0, 0);
    o = __builtin_amdgcn_mfma_f32_32x32x16_bf16(va2.s, b2.s, o, 0, 0, 0);
  }

  // ---- stage partials to LDS ----
  lsum += __shfl_xor(lsum, 32);          // full per-query l over this wave's keys
  if (half == 0) l_lds[wav][l31] = lsum;
  #pragma unroll
  for (int r = 0; r < 16; ++r)
    po_lds[wav][r][lane] = f2bf(o[r]);
  __syncthreads();

  // ---- reduce over the 16 waves: one thread per (reg, lane) cell ----
  int rr = tid >> 6;                     // 0..15
  int ii = tid & 63;
  float oval = 0.f;
  #pragma unroll
  for (int w = 0; w < 16; ++w) oval += bf2f(po_lds[w][rr][ii]);
  if (tid < 32) {
    float L = 0.f;
    #pragma unroll
    for (int w = 0; w < 16; ++w) L += l_lds[w][tid];
    Lrcp[tid] = 1.f / L;                 // L > 0 always (p > 0)
  }
  __syncthreads();

  int cc = (rr & 3) + 8 * (rr >> 2) + 4 * (ii >> 5);   // channel
  int jq = ii & 31;                                    // query within tile
  ot[cc][jq] = oval * Lrcp[jq];
  __syncthreads();

  // ---- w_o projection + residual: thread -> 2 output rows ----
  int j2  = tid & 31;
  int ocp = tid >> 5;                    // 0..31
  int oc0 = ocp;
  int oc1 = ocp + 32;
  float acc0 = 0.f, acc1 = 0.f;
  #pragma unroll
  for (int c = 0; c < DV; ++c) {
    float ov = ot[c][j2];
    acc0 = fmaf(wsh[oc0 * DV + c], ov, acc0);
    acc1 = fmaf(wsh[oc1 * DV + c], ov, acc1);
  }
  size_t base = (size_t)b * C * N + (size_t)qt * 32 + j2;
  out[base + (size_t)oc0 * N] = acc0 + x[base + (size_t)oc0 * N];
  out[base + (size_t)oc1 * N] = acc1 + x[base + (size_t)oc1 * N];
}

// ---------------------------------------------------------------------------
extern "C" void kernel_launch(void* const* d_in, const int* in_sizes, int n_in,
                              void* d_out, int out_size, void* d_ws, size_t ws_size,
                              hipStream_t stream) {
  const float* x       = (const float*)d_in[0];
  const float* w_theta = (const float*)d_in[1];
  const float* w_phi   = (const float*)d_in[2];
  const float* w_g     = (const float*)d_in[3];
  const float* w_o     = (const float*)d_in[4];
  const float* gamma   = (const float*)d_in[5];
  const float* u_theta = (const float*)d_in[6];
  const float* u_phi   = (const float*)d_in[8];
  const float* u_g     = (const float*)d_in[10];
  const float* u_o     = (const float*)d_in[12];
  float* out = (float*)d_out;

  float* ws = (float*)d_ws;
  float*          scales   = ws;                                   // 16 floats
  unsigned short* theta_bf = (unsigned short*)(ws + 16);           // B*N*8 bf16
  unsigned short* phi_bf   = theta_bf + (size_t)B * N * 8;         // B*N*8
  unsigned short* v_bf     = phi_bf   + (size_t)B * N * 8;         // B*DV*N

  projsig_kernel<<<PROJ_BLOCKS + 4, 256, 0, stream>>>(
      x, w_theta, w_phi, w_g, w_o, u_theta, u_phi, u_g, u_o,
      scales, theta_bf, phi_bf, v_bf);
  attn_kernel<<<B * 128, 1024, 0, stream>>>(
      theta_bf, phi_bf, v_bf, w_o, scales, gamma, x, out);
}

// Round 7
// 123.639 us; speedup vs baseline: 3.6408x; 1.0595x over previous
//
#include <hip/hip_runtime.h>
#include <math.h>

// Problem constants (B,C,H,W = 4,64,64,64)
#define N     4096          // H*W
#define B     4
#define C     64
#define DQK   8
#define DV    32
#define LOG2E 1.4426950408889634f
#define PROJ_BLOCKS ((B * 12 * N) / 256)   // 768

typedef __attribute__((ext_vector_type(8)))  short  short8;   // 8 bf16 (4 VGPR)
typedef __attribute__((ext_vector_type(16))) float  float16;  // MFMA 32x32 acc

union U4S8 { int4 v; unsigned int u[4]; short8 s; };

__device__ __forceinline__ unsigned short f2bf(float f) {   // RNE
  union { float f; unsigned int u; } c; c.f = f;
  unsigned int r = c.u + 0x7FFF + ((c.u >> 16) & 1);
  return (unsigned short)(r >> 16);
}
__device__ __forceinline__ float bf2f(unsigned short h) {
  union { unsigned int u; float f; } c; c.u = ((unsigned int)h) << 16;
  return c.f;
}
__device__ __forceinline__ unsigned int fbits(float f) {
  union { float f; unsigned int u; } c; c.f = f; return c.u;
}
__device__ __forceinline__ int bitswap23(int n) {   // swap bits 2<->3 (involution)
  return (n & ~0xC) | ((n & 4) << 1) | ((n & 8) >> 1);
}

// ---------------------------------------------------------------------------
// Kernel 1 (fat): blocks [0,768) = projections -> UNSCALED bf16 buffers;
// blocks [768,772) = spectral-norm sigma (concurrent; scales consumed only by
// the attention kernel).
//   proj thread = (b, n, quad g in [0,12)):
//     g 0-1: theta rows -> theta_bf[b][n][8]
//     g 2-3: phi  rows -> phi_bf  [b][n][8]
//     g 4-11: g  rows -> v_pack[b][q][lane][8]: MFMA A-fragment order with the
//             bitswap23 key permutation baked in, so attn's va loads are
//             lane-consecutive 16B (no gather) and score C-layout regs feed
//             the PV B-operand with no cross-lane exchange.
// ---------------------------------------------------------------------------
__global__ __launch_bounds__(256) void projsig_kernel(
    const float* __restrict__ x,
    const float* __restrict__ w_theta, const float* __restrict__ w_phi,
    const float* __restrict__ w_g,     const float* __restrict__ w_o,
    const float* __restrict__ u_theta, const float* __restrict__ u_phi,
    const float* __restrict__ u_g,     const float* __restrict__ u_o,
    float* __restrict__ scales,
    unsigned short* __restrict__ theta_bf,
    unsigned short* __restrict__ phi_bf,
    unsigned short* __restrict__ v_pack) {
  __shared__ float v1[64];
  int bid = blockIdx.x;
  int tid = threadIdx.x;

  if (bid >= PROJ_BLOCKS) {
    // ---- sigma: 1/sigma, sigma = ||t||^2/(||t||+eps), t = w * l2n(w^T u) ----
    int which = bid - PROJ_BLOCKS;
    const float* w; const float* u; int M, K;
    if      (which == 0) { w = w_theta; u = u_theta; M = DQK; K = C;  }
    else if (which == 1) { w = w_phi;   u = u_phi;   M = DQK; K = C;  }
    else if (which == 2) { w = w_g;     u = u_g;     M = DV;  K = C;  }
    else                 { w = w_o;     u = u_o;     M = C;   K = DV; }

    float acc = 0.f;
    if (tid < K) {
      for (int m = 0; m < M; ++m) acc += w[m * K + tid] * u[m];
    }
    float ss = acc * acc;
    #pragma unroll
    for (int off = 32; off; off >>= 1) ss += __shfl_xor(ss, off);
    float nrm = sqrtf(ss);
    if (tid < 64) v1[tid] = (tid < K) ? acc / (nrm + 1e-12f) : 0.f;
    __syncthreads();

    float t = 0.f;
    if (tid < M) {
      for (int k = 0; k < K; ++k) t += w[tid * K + k] * v1[k];
    }
    float ts = t * t;
    #pragma unroll
    for (int off = 32; off; off >>= 1) ts += __shfl_xor(ts, off);
    float tn = sqrtf(ts);
    if (tid == 0) scales[which] = (tn + 1e-12f) / ts;
    return;
  }

  // ---- projections ----
  int t  = bid * 256 + tid;   // [0, B*12*N)
  int n  = t & (N - 1);
  int bg = t >> 12;
  int g  = bg % 12;           // block-uniform
  int b  = bg / 12;

  const float* xp = x + (size_t)b * C * N + n;
  float xv[C];
  #pragma unroll
  for (int c = 0; c < C; ++c) xv[c] = xp[(size_t)c * N];

  const float* wbase;
  if      (g < 2) wbase = w_theta + g * 4 * C;
  else if (g < 4) wbase = w_phi + (g - 2) * 4 * C;
  else            wbase = w_g + (g - 4) * 4 * C;

  float o[4];
  #pragma unroll
  for (int r = 0; r < 4; ++r) {
    const float* wr = wbase + r * C;
    float a = 0.f;
    #pragma unroll
    for (int c = 0; c < C; ++c) a += wr[c] * xv[c];
    o[r] = a;
  }

  if (g < 4) {
    unsigned int lo = ((unsigned int)f2bf(o[0])) | ((unsigned int)f2bf(o[1]) << 16);
    unsigned int hi = ((unsigned int)f2bf(o[2])) | ((unsigned int)f2bf(o[3]) << 16);
    unsigned short* dst = (g < 2) ? theta_bf : phi_bf;
    int sub = g & 1;
    int2 pk; pk.x = (int)lo; pk.y = (int)hi;
    *(int2*)(dst + ((size_t)b * N + n) * 8 + sub * 4) = pk;
  } else {
    int c0 = (g - 4) * 4;
    // slot index in permuted key space
    int m  = bitswap23(n);
    int q  = m >> 4;            // 16-key chunk
    int hf = (m >> 3) & 1;      // which half of the chunk
    int ii = m & 7;             // element within the 8-pack
    unsigned short* dst = v_pack + ((size_t)(b * 256 + q)) * 64 * 8;
    #pragma unroll
    for (int r = 0; r < 4; ++r) {
      int lane = (c0 + r) | (hf << 5);
      dst[lane * 8 + ii] = f2bf(o[r]);
    }
  }
}

// ---------------------------------------------------------------------------
// Kernel 2: fully fused MFMA attention + combine + w_o projection + residual.
// Block = 1024 threads (16 waves) = one query tile (32 queries) x ALL keys;
// wave w handles keys [w*256, w*256+256). No online max (scores bounded by
// spectral norm; exp2 domain safe). kappa = s0*s1*log2e pre-folded into the
// phi B-fragment (bf16, same relative precision). Per 32-key tile:
// 3 coalesced dwordx4 loads, 1 score MFMA, 16 exp2+add, 8 packs, 2 PV MFMAs.
// Epilogue: fp32 LDS merge of 16 waves' (o[16regs], l), normalize, then
// out[64,32] = (s2*s3*gamma) * w_o @ o + x written directly.
// ---------------------------------------------------------------------------
__global__ __launch_bounds__(1024) void attn_kernel(
    const unsigned short* __restrict__ theta_bf,
    const unsigned short* __restrict__ phi_bf,
    const unsigned short* __restrict__ v_pack,
    const float* __restrict__ w_o, const float* __restrict__ scales,
    const float* __restrict__ gamma,
    const float* __restrict__ x, float* __restrict__ out) {
  __shared__ float po_lds[16][16][64];           // [wave][reg][lane] 64 KB
  __shared__ float l_lds[16][32];                // 2 KB
  __shared__ float Lrcp[32];
  __shared__ float ot[DV][33];                   // normalized o tile, padded
  __shared__ float wsh[C * DV];                  // scaled w_o, 8 KB

  int bi = blockIdx.x;           // B * 128
  int qt = bi & 127;
  int b  = bi >> 7;
  int tid  = threadIdx.x;
  int lane = tid & 63;
  int wav  = tid >> 6;           // 0..15
  int half = lane >> 5;
  int l31  = lane & 31;
  int j    = qt * 32 + l31;      // query column

  float kappa = scales[0] * scales[1] * LOG2E;
  float swo   = scales[2] * scales[3] * gamma[0];
  for (int i = tid; i < C * DV; i += 1024) wsh[i] = w_o[i] * swo;

  // phi B-frag: lane(n=j, k=half*8+i); zero high K-half (dqk=8 pad to 16).
  // kappa folded in here once (O(5) values: bf16 relative precision unchanged).
  U4S8 phu; phu.u[0] = phu.u[1] = phu.u[2] = phu.u[3] = 0;
  if (half == 0) {
    U4S8 raw; raw.v = *(const int4*)(phi_bf + ((size_t)b * N + j) * 8);
    #pragma unroll
    for (int i = 0; i < 8; ++i)
      phu.s[i] = (short)f2bf(bf2f((unsigned short)raw.s[i]) * kappa);
  }
  short8 phB = phu.s;

  float lsum = 0.f;
  float16 o;
  #pragma unroll
  for (int r = 0; r < 16; ++r) o[r] = 0.f;

  int kstart = wav * 256;

  #pragma unroll 2
  for (int tt = 0; tt < 8; ++tt) {
    int kb = kstart + tt * 32;
    int q1 = kb >> 4;            // 16-key chunk index (block-uniform)

    U4S8 ta;  ta.v  = *(const int4*)(theta_bf + ((size_t)b * N + kb + l31) * 8);
    const int4* vp = (const int4*)(v_pack + ((size_t)(b * 256 + q1)) * 64 * 8);
    U4S8 va1; va1.v = vp[lane];        // coalesced 16B/lane
    U4S8 va2; va2.v = vp[64 + lane];

    float16 sf;
    #pragma unroll
    for (int r = 0; r < 16; ++r) sf[r] = 0.f;
    sf = __builtin_amdgcn_mfma_f32_32x32x16_bf16(ta.s, phB, sf, 0, 0, 0);

    float p[16];
    #pragma unroll
    for (int r = 0; r < 16; ++r) {
      p[r] = exp2f(sf[r]);
      lsum += p[r];
    }

    unsigned int pk[8];
    #pragma unroll
    for (int i = 0; i < 8; ++i)
      pk[i] = __builtin_amdgcn_perm(fbits(p[2 * i + 1]), fbits(p[2 * i]),
                                    0x07060302u);
    // V is stored key-permuted: C-layout regs ARE the B-operand fragments.
    U4S8 b1, b2;
    b1.u[0] = pk[0]; b1.u[1] = pk[1]; b1.u[2] = pk[2]; b1.u[3] = pk[3];
    b2.u[0] = pk[4]; b2.u[1] = pk[5]; b2.u[2] = pk[6]; b2.u[3] = pk[7];

    o = __builtin_amdgcn_mfma_f32_32x32x16_bf16(va1.s, b1.s, o, 0, 0, 0);
    o = __builtin_amdgcn_mfma_f32_32x32x16_bf16(va2.s, b2.s, o, 0, 0, 0);
  }

  // ---- stage partials to LDS (fp32) ----
  lsum += __shfl_xor(lsum, 32);          // full per-query l over this wave's keys
  if (half == 0) l_lds[wav][l31] = lsum;
  #pragma unroll
  for (int r = 0; r < 16; ++r)
    po_lds[wav][r][lane] = o[r];
  __syncthreads();

  // ---- reduce over the 16 waves: one thread per (reg, lane) cell ----
  int rr = tid >> 6;                     // 0..15
  int ii = tid & 63;
  float oval = 0.f;
  #pragma unroll
  for (int w = 0; w < 16; ++w) oval += po_lds[w][rr][ii];
  if (tid < 32) {
    float L = 0.f;
    #pragma unroll
    for (int w = 0; w < 16; ++w) L += l_lds[w][tid];
    Lrcp[tid] = 1.f / L;                 // L > 0 always (p > 0)
  }
  __syncthreads();

  int cc = (rr & 3) + 8 * (rr >> 2) + 4 * (ii >> 5);   // channel
  int jq = ii & 31;                                    // query within tile
  ot[cc][jq] = oval * Lrcp[jq];
  __syncthreads();

  // ---- w_o projection + residual: thread -> 2 output rows ----
  int j2  = tid & 31;
  int ocp = tid >> 5;                    // 0..31
  int oc0 = ocp;
  int oc1 = ocp + 32;
  float acc0 = 0.f, acc1 = 0.f;
  #pragma unroll
  for (int c = 0; c < DV; ++c) {
    float ov = ot[c][j2];
    acc0 = fmaf(wsh[oc0 * DV + c], ov, acc0);
    acc1 = fmaf(wsh[oc1 * DV + c], ov, acc1);
  }
  size_t base = (size_t)b * C * N + (size_t)qt * 32 + j2;
  out[base + (size_t)oc0 * N] = acc0 + x[base + (size_t)oc0 * N];
  out[base + (size_t)oc1 * N] = acc1 + x[base + (size_t)oc1 * N];
}

// ---------------------------------------------------------------------------
extern "C" void kernel_launch(void* const* d_in, const int* in_sizes, int n_in,
                              void* d_out, int out_size, void* d_ws, size_t ws_size,
                              hipStream_t stream) {
  const float* x       = (const float*)d_in[0];
  const float* w_theta = (const float*)d_in[1];
  const float* w_phi   = (const float*)d_in[2];
  const float* w_g     = (const float*)d_in[3];
  const float* w_o     = (const float*)d_in[4];
  const float* gamma   = (const float*)d_in[5];
  const float* u_theta = (const float*)d_in[6];
  const float* u_phi   = (const float*)d_in[8];
  const float* u_g     = (const float*)d_in[10];
  const float* u_o     = (const float*)d_in[12];
  float* out = (float*)d_out;

  float* ws = (float*)d_ws;
  float*          scales   = ws;                                   // 16 floats
  unsigned short* theta_bf = (unsigned short*)(ws + 16);           // B*N*8 bf16
  unsigned short* phi_bf   = theta_bf + (size_t)B * N * 8;         // B*N*8
  unsigned short* v_pack   = phi_bf   + (size_t)B * N * 8;         // B*256*64*8

  projsig_kernel<<<PROJ_BLOCKS + 4, 256, 0, stream>>>(
      x, w_theta, w_phi, w_g, w_o, u_theta, u_phi, u_g, u_o,
      scales, theta_bf, phi_bf, v_pack);
  attn_kernel<<<B * 128, 1024, 0, stream>>>(
      theta_bf, phi_bf, v_pack, w_o, scales, gamma, x, out);
}